// Round 15
// baseline (365.862 us; speedup 1.0000x reference)
//
#include <hip/hip_runtime.h>

// DiffeomorphicLearnerTorch, R19 = R18 (361.1us, session best) + consumer
// bw prefetch-before-barrier (T14, isolated).
// R18 post-mortem: af-resident + Zj-through-LDS WIN (-5.5us) — producer's
// per-tile L2 exposure removed. Last exposed window: consumer issues its 8
// ATf bw frags AFTER barrier release, right before PV -> ~300-500cyc L2/L3
// round-trip on every tile's critical path. Consumer is the EARLY-arriving
// role (producer phase heavier), so issuing bw BEFORE the barrier hides the
// full latency under the barrier wait. This is R15's consumer rotation in
// isolation: R15 bundled it with producer bv rotation on a base with 16
// producer global loads in flight (regressed +0.6us/launch); R18's producer
// has ZERO per-tile global loads, so the interaction is gone.
// Consumer regs ~119 <= 128 cap; producer untouched; math identical
// (verified absmax 0.015625).
// Per step: Z += DT*(Z@Aaff^T + b + [ei*ej*exp(2*C1*Z@Z^T)]@A_t)
// Frag-linear layouts (verified R4/R5):
//   Zf  [128 jblk][16 ks][64 lane]x8 bf16
//   ATf [t][8 dblk][256 jb][64 lane]x8 bf16

#define N_PTS 4096
#define DIM   256
#define DT_C  0.125f
#define C1    (1.0f/512.0f)

typedef __bf16 bf16x8 __attribute__((ext_vector_type(8)));
typedef float  f32x16 __attribute__((ext_vector_type(16)));
typedef float  f32x4v __attribute__((ext_vector_type(4)));
typedef unsigned int   u32x4 __attribute__((ext_vector_type(4)));
typedef unsigned short u16x8 __attribute__((ext_vector_type(8)));

__device__ __forceinline__ unsigned short f2bf(float f) {
  unsigned int u = __builtin_bit_cast(unsigned int, f);
  u += 0x7fffu + ((u >> 16) & 1u);          // RNE
  return (unsigned short)(u >> 16);
}
__device__ __forceinline__ float bf2f(unsigned short s) {
  unsigned int u = ((unsigned int)s) << 16;
  return __builtin_bit_cast(float, u);
}

typedef __attribute__((address_space(1))) const unsigned int gas_u32;
typedef __attribute__((address_space(3))) unsigned int las_u32;
__device__ __forceinline__ void gload_lds16(const void* g, void* l) {
  __builtin_amdgcn_global_load_lds((gas_u32*)g, (las_u32*)l, 16, 0, 0);
}

// ---- ATf: A[t][4096][256] f32 -> frag-linear bf16 B-operand tiles ----
__global__ __launch_bounds__(256) void k_prep(const float* __restrict__ A,
                                              unsigned short* __restrict__ ATf) {
  __shared__ float sT[64][36];
  const int jgrp = blockIdx.x, ds = blockIdx.y, t = blockIdx.z;
  const int tid = threadIdx.x;
  const float* Ab = A + (size_t)t * N_PTS * DIM;
  {
    const int j_l = tid >> 2, dq = tid & 3;
    const float* src = Ab + (size_t)(jgrp * 64 + j_l) * DIM + ds * 32 + dq * 8;
    f32x4v v0 = *(const f32x4v*)src, v1 = *(const f32x4v*)(src + 4);
    *(f32x4v*)&sT[j_l][dq * 8] = v0;
    *(f32x4v*)&sT[j_l][dq * 8 + 4] = v1;
  }
  __syncthreads();
  const int jb_l = tid >> 6, l = tid & 63, l31 = l & 31, lhi = l >> 5;
  u16x8 o;
#pragma unroll
  for (int e = 0; e < 8; ++e) o[e] = f2bf(sT[jb_l * 16 + lhi * 8 + e][l31]);
  unsigned short* dst = ATf + (size_t)t * (8 * 256 * 64 * 8)
                      + ((size_t)(ds * 256 + jgrp * 4 + jb_l) * 64 + l) * 8;
  *(u16x8*)dst = o;
}

// ---- init: X -> Zf frags + erow ----
__global__ __launch_bounds__(256) void k_init(const float* __restrict__ X,
                                              unsigned short* __restrict__ Zf,
                                              float* __restrict__ erow) {
  const int tid = threadIdx.x;
  const int r = blockIdx.x * 8 + (tid >> 5), o = tid & 31;
  const size_t base = (size_t)r * DIM + o * 8;
  f32x4v z0 = *(const f32x4v*)(X + base), z1 = *(const f32x4v*)(X + base + 4);
  u16x8 zb; float s = 0.f;
#pragma unroll
  for (int i = 0; i < 4; ++i) { zb[i] = f2bf(z0[i]); zb[4 + i] = f2bf(z1[i]);
                                s += z0[i] * z0[i] + z1[i] * z1[i]; }
  *(u16x8*)(Zf + ((size_t)((r >> 5) * 16 + (o >> 1)) * 64 + (o & 1) * 32 + (r & 31)) * 8) = zb;
#pragma unroll
  for (int d = 16; d > 0; d >>= 1) s += __shfl_down(s, d, 32);
  if (o == 0) erow[r] = __expf(-s * C1);
}

// ---- fused flash (R18 structure + consumer bw prefetch) ----
// grid (8 chunks, 64 i-tiles of 64 rows), 512 thr = 8 waves, 2 blocks/CU.
// waves 0-3 producer (ip=wid>>1, jh=wid&1): S = Zi(32) @ Zj(32)^T;
//   af[16] RESIDENT (global, once); bv from sZj[cur] (ds_read); producers
//   stage sZj[(n+1)&1] via 8x gload_lds16/thread. P -> sP[n&1].
// waves 4-7 consumer cd: O(64i x 64d) += P @ A_t; bw x8 PREFETCHED before
//   each barrier (hides L2/L3 under barrier wait); + affine slice.
__global__ __launch_bounds__(512, 4) void k_flash(
    const unsigned short* __restrict__ Zf, const float* __restrict__ erow,
    const unsigned short* __restrict__ ATf_t,
    const float* __restrict__ Aaff_t,
    unsigned short* __restrict__ Opart) {
  __shared__ __align__(16) unsigned short sP[2][64 * 64];       // 2 x 8KB swizzled
  __shared__ __align__(16) unsigned short sZj[2][2 * 16 * 64 * 8]; // 2 x 32KB

  const int tid = threadIdx.x, lane = tid & 63, wid = tid >> 6;
  const int l31 = lane & 31, lhi = lane >> 5;
  const int chunk = blockIdx.x;
  const int i0 = blockIdx.y * 64;
  const int ib = i0 >> 5;
  const unsigned short* zib = Zf + (size_t)ib * 8192;           // 64 i-rows, frag-linear
  const unsigned short* zjs = Zf + (size_t)(chunk * 16) * 8192; // chunk j-region

  if (wid < 4) {
    // ================= producer =================
    const int ip = wid >> 1, jh = wid & 1;

    // stage tile 0 (32KB over 256 producer threads: 8 x 16B each)
#pragma unroll
    for (int p = 0; p < 8; ++p)
      gload_lds16(zjs + (size_t)(p * 256 + tid) * 8,
                  sZj[0] + (size_t)(p * 256 + tid) * 8);

    // af[16] resident: wave's 32 i-rows x K=256, from global (once)
    u32x4 af[16];
#pragma unroll
    for (int ks = 0; ks < 16; ++ks)
      af[ks] = *(const u32x4*)(zib + ((size_t)(ip * 16 + ks) * 64 + lane) * 8);

    const float* eIb = erow + i0 + ip * 32 + 4 * lhi;   // + (c&3) + 8*(c>>2)
    __syncthreads();   // stage barrier: sZj[0] ready (vmcnt drained)

    for (int n = 0; n < 8; ++n) {
      const int cur = n & 1;
      // stage tile n+1 into the other buffer (async; drained at barrier)
      if (n < 7) {
        const unsigned short* src = zjs + (size_t)(n + 1) * 16384;
#pragma unroll
        for (int p = 0; p < 8; ++p)
          gload_lds16(src + (size_t)(p * 256 + tid) * 8,
                      sZj[cur ^ 1] + (size_t)(p * 256 + tid) * 8);
      }
      // S chain: af (regs) x bv (LDS ds_read_b128, ~120cyc, prefetchable)
      f32x16 S;
#pragma unroll
      for (int i = 0; i < 16; ++i) S[i] = 0.f;
      __builtin_amdgcn_s_setprio(1);
#pragma unroll
      for (int ks = 0; ks < 16; ++ks) {
        bf16x8 bv = *(const bf16x8*)(sZj[cur] + ((size_t)(jh * 16 + ks) * 64 + lane) * 8);
        S = __builtin_amdgcn_mfma_f32_32x32x16_bf16(
            __builtin_bit_cast(bf16x8, af[ks]), bv, S, 0, 0, 0);
      }
      __builtin_amdgcn_s_setprio(0);
      const float ej = erow[chunk * 512 + n * 64 + jh * 32 + l31];
      unsigned short* pb = sP[n & 1];
      const int blk = jh * 4 + (l31 >> 3), cl = l31 & 7;
#pragma unroll
      for (int c = 0; c < 16; ++c) {
        const int row = ip * 32 + 4 * lhi + (c & 3) + 8 * (c >> 2);
        const float eIc = eIb[(c & 3) + 8 * (c >> 2)];   // L1-hot broadcast
        pb[row * 64 + ((blk ^ (row & 7)) * 8) + cl] =
            f2bf(eIc * ej * __expf(2.f * C1 * S[c]));
      }
      __syncthreads();
    }
    __syncthreads();   // match consumer's final barrier
  } else {
    // ================= consumer =================
    const int cd = wid - 4;
    f32x16 O[2][2];
#pragma unroll
    for (int rs = 0; rs < 2; ++rs)
#pragma unroll
      for (int ct = 0; ct < 2; ++ct)
#pragma unroll
        for (int i = 0; i < 16; ++i) O[rs][ct][i] = 0.f;

    // tile-0 bw prefetch: issued BEFORE the stage+tile0 barriers — the
    // L2/L3 round-trip hides under the producer's staging + tile-0 S-chain.
    u32x4 bw[8];
#pragma unroll
    for (int ks = 0; ks < 4; ++ks)
#pragma unroll
      for (int ct = 0; ct < 2; ++ct)
        bw[ks * 2 + ct] = *(const u32x4*)(ATf_t +
            ((size_t)((cd * 2 + ct) * 256 + chunk * 32 + ks) * 64 + lane) * 8);

    // affine slice (unscaled): ksg = chunk*2+{0,1}; a-frags from GLOBAL
#pragma unroll
    for (int q = 0; q < 2; ++q) {
      const int ksg = chunk * 2 + q;
      bf16x8 a[2];
#pragma unroll
      for (int rs = 0; rs < 2; ++rs)
        a[rs] = *(const bf16x8*)(zib + ((size_t)(rs * 16 + ksg) * 64 + lane) * 8);
#pragma unroll
      for (int ct = 0; ct < 2; ++ct) {
        const int d = cd * 64 + ct * 32 + l31;
        const float* bp = Aaff_t + (size_t)d * DIM + ksg * 16 + lhi * 8;
        f32x4v f0 = *(const f32x4v*)bp, f1 = *(const f32x4v*)(bp + 4);
        u16x8 tb;
#pragma unroll
        for (int i = 0; i < 4; ++i) { tb[i] = f2bf(f0[i]); tb[4 + i] = f2bf(f1[i]); }
        bf16x8 bv = __builtin_bit_cast(bf16x8, tb);
#pragma unroll
        for (int rs = 0; rs < 2; ++rs)
          O[rs][ct] = __builtin_amdgcn_mfma_f32_32x32x16_bf16(a[rs], bv, O[rs][ct], 0, 0, 0);
      }
    }
    __syncthreads();   // stage barrier (producers staged sZj[0])
    __syncthreads();   // barrier 1 (producer finished tile 0)

    for (int n = 1; n <= 8; ++n) {
      const int m = n - 1;
      const unsigned short* pb = sP[m & 1];
#pragma unroll
      for (int ks = 0; ks < 4; ++ks) {
        bf16x8 a[2];
        const int blk = ks * 2 + lhi;
#pragma unroll
        for (int rs = 0; rs < 2; ++rs) {
          const int row = rs * 32 + l31;
          a[rs] = *(const bf16x8*)&pb[row * 64 + ((blk ^ (row & 7)) * 8)];
        }
        __builtin_amdgcn_s_setprio(1);
#pragma unroll
        for (int rs = 0; rs < 2; ++rs)
#pragma unroll
          for (int ct = 0; ct < 2; ++ct)
            O[rs][ct] = __builtin_amdgcn_mfma_f32_32x32x16_bf16(
                a[rs], __builtin_bit_cast(bf16x8, bw[ks * 2 + ct]), O[rs][ct], 0, 0, 0);
        __builtin_amdgcn_s_setprio(0);
      }
      // prefetch next tile's bw BEFORE the barrier: the L2/L3 latency hides
      // under the barrier wait (consumer is the early-arriving role).
      if (n < 8) {
#pragma unroll
        for (int ks = 0; ks < 4; ++ks)
#pragma unroll
          for (int ct = 0; ct < 2; ++ct)
            bw[ks * 2 + ct] = *(const u32x4*)(ATf_t +
                ((size_t)((cd * 2 + ct) * 256 + chunk * 32 + m * 4 + 4 + ks) * 64 + lane) * 8);
      }
      __syncthreads();
    }

    // epilogue -> Opart[chunk] bf16 (P already carries ei*ej)
    unsigned short* ob = Opart + (size_t)chunk * N_PTS * DIM + (size_t)cd * 64 + l31;
#pragma unroll
    for (int rs = 0; rs < 2; ++rs)
#pragma unroll
      for (int c = 0; c < 16; ++c) {
        const int row = i0 + rs * 32 + 4 * lhi + (c & 3) + 8 * (c >> 2);
        ob[(size_t)row * DIM]      = f2bf(O[rs][0][c]);
        ob[(size_t)row * DIM + 32] = f2bf(O[rs][1][c]);
      }
  }
}

// ---- update: Z += DT*(sum partials + baff); emit Zf frags + erow ----
__global__ __launch_bounds__(256) void k_update(const float* __restrict__ Zin,
                                                const unsigned short* __restrict__ Opart,
                                                const float* __restrict__ baff_t,
                                                float* __restrict__ Zout,
                                                unsigned short* __restrict__ Zf,
                                                float* __restrict__ erow) {
  const int tid = threadIdx.x;
  const int r = blockIdx.x * 8 + (tid >> 5), o = tid & 31;
  const size_t base = (size_t)r * DIM + o * 8;
  f32x4v z0 = *(const f32x4v*)(Zin + base), z1 = *(const f32x4v*)(Zin + base + 4);
  f32x4v s0 = *(const f32x4v*)(baff_t + o * 8), s1 = *(const f32x4v*)(baff_t + o * 8 + 4);
#pragma unroll
  for (int c = 0; c < 8; ++c) {
    u16x8 p = *(const u16x8*)(Opart + (size_t)c * N_PTS * DIM + base);
#pragma unroll
    for (int i = 0; i < 4; ++i) { s0[i] += bf2f(p[i]); s1[i] += bf2f(p[4 + i]); }
  }
  u16x8 zb; float sv = 0.f;
#pragma unroll
  for (int i = 0; i < 4; ++i) {
    z0[i] += DT_C * s0[i]; z1[i] += DT_C * s1[i];
    zb[i] = f2bf(z0[i]); zb[4 + i] = f2bf(z1[i]);
    sv += z0[i] * z0[i] + z1[i] * z1[i];
  }
  *(f32x4v*)(Zout + base) = z0;
  *(f32x4v*)(Zout + base + 4) = z1;
  *(u16x8*)(Zf + ((size_t)((r >> 5) * 16 + (o >> 1)) * 64 + (o & 1) * 32 + (r & 31)) * 8) = zb;
#pragma unroll
  for (int d = 16; d > 0; d >>= 1) sv += __shfl_down(sv, d, 32);
  if (o == 0) erow[r] = __expf(-sv * C1);
}

extern "C" void kernel_launch(void* const* d_in, const int* in_sizes, int n_in,
                              void* d_out, int out_size, void* d_ws, size_t ws_size,
                              hipStream_t stream) {
  const float* X    = (const float*)d_in[0];
  const float* A    = (const float*)d_in[1];
  const float* Aaff = (const float*)d_in[2];
  const float* baff = (const float*)d_in[3];
  float* out = (float*)d_out;

  char* w = (char*)d_ws;
  size_t off = 0;
  unsigned short* ATf = (unsigned short*)(w + off); off += (size_t)8 * 8 * 256 * 64 * 8 * 2; // 16 MiB
  unsigned short* Zf  = (unsigned short*)(w + off); off += (size_t)N_PTS * DIM * 2;          // 2 MiB
  float* erow = (float*)(w + off); off += (size_t)N_PTS * 4;
  float* Zf32 = (float*)(w + off); off += (size_t)N_PTS * DIM * 4;                           // 4 MiB
  unsigned short* Opart = (unsigned short*)(w + off); off += (size_t)8 * N_PTS * DIM * 2;    // 16 MiB
  (void)ws_size; (void)in_sizes; (void)n_in; (void)out_size;

  k_prep<<<dim3(64, 8, 8), 256, 0, stream>>>(A, ATf);
  k_init<<<512, 256, 0, stream>>>(X, Zf, erow);

  const float* zin = X;
  for (int t = 0; t < 8; ++t) {
    float* zout = (t == 7) ? out : Zf32;  // in-place safe after t=0
    k_flash<<<dim3(8, 64), 512, 0, stream>>>(
        Zf, erow, ATf + (size_t)t * (8 * 256 * 64 * 8), Aaff + (size_t)t * DIM * DIM, Opart);
    k_update<<<512, 256, 0, stream>>>(zin, Opart, baff + (size_t)t * DIM, zout, Zf, erow);
    zin = zout;
  }
}

// Round 16
// 362.043 us; speedup vs baseline: 1.0105x; 1.0105x over previous
//
#include <hip/hip_runtime.h>

// DiffeomorphicLearnerTorch, R20 = R18 verbatim (session best, 361.1us).
// R19 post-mortem: consumer bw prefetch-before-barrier REGRESSED (365.9)
// — extending bw[8] live range across the barrier pinned 32 VGPRs through
// the wait for zero latency benefit (operand latency in this role-split
// structure is covered by cross-wave TLP; confirmed twice, R15 + R19).
// Session verdict: all throughput pipes <=30%; individually exonerated:
// VALU count (R10), L2 operand path (R11), staging depth (R12), occupancy
// regime (R13), barrier count (R16), chain ILP (R17), operand prefetch
// (R15/R19 hurt). Wins: role-aware setprio (-14us, R14), producer
// reg+LDS operand path (-5.5us, R18). Structural constraint: 128-VGPR cap
// (8 waves x 2 blocks/CU, resident O-tiles) -> 4 waves/SIMD whose serial
// tails convoy at per-tile barriers. Reverting to best-known-good.
// Structure: producers af[16]-resident + Zj double-buffered via
// global_load_lds; consumers PV from sP + per-tile bw hoist (R14 placement).
// Per step: Z += DT*(Z@Aaff^T + b + [ei*ej*exp(2*C1*Z@Z^T)]@A_t)
// Frag-linear layouts (verified R4/R5):
//   Zf  [128 jblk][16 ks][64 lane]x8 bf16
//   ATf [t][8 dblk][256 jb][64 lane]x8 bf16

#define N_PTS 4096
#define DIM   256
#define DT_C  0.125f
#define C1    (1.0f/512.0f)

typedef __bf16 bf16x8 __attribute__((ext_vector_type(8)));
typedef float  f32x16 __attribute__((ext_vector_type(16)));
typedef float  f32x4v __attribute__((ext_vector_type(4)));
typedef unsigned int   u32x4 __attribute__((ext_vector_type(4)));
typedef unsigned short u16x8 __attribute__((ext_vector_type(8)));

__device__ __forceinline__ unsigned short f2bf(float f) {
  unsigned int u = __builtin_bit_cast(unsigned int, f);
  u += 0x7fffu + ((u >> 16) & 1u);          // RNE
  return (unsigned short)(u >> 16);
}
__device__ __forceinline__ float bf2f(unsigned short s) {
  unsigned int u = ((unsigned int)s) << 16;
  return __builtin_bit_cast(float, u);
}

typedef __attribute__((address_space(1))) const unsigned int gas_u32;
typedef __attribute__((address_space(3))) unsigned int las_u32;
__device__ __forceinline__ void gload_lds16(const void* g, void* l) {
  __builtin_amdgcn_global_load_lds((gas_u32*)g, (las_u32*)l, 16, 0, 0);
}

// ---- ATf: A[t][4096][256] f32 -> frag-linear bf16 B-operand tiles ----
__global__ __launch_bounds__(256) void k_prep(const float* __restrict__ A,
                                              unsigned short* __restrict__ ATf) {
  __shared__ float sT[64][36];
  const int jgrp = blockIdx.x, ds = blockIdx.y, t = blockIdx.z;
  const int tid = threadIdx.x;
  const float* Ab = A + (size_t)t * N_PTS * DIM;
  {
    const int j_l = tid >> 2, dq = tid & 3;
    const float* src = Ab + (size_t)(jgrp * 64 + j_l) * DIM + ds * 32 + dq * 8;
    f32x4v v0 = *(const f32x4v*)src, v1 = *(const f32x4v*)(src + 4);
    *(f32x4v*)&sT[j_l][dq * 8] = v0;
    *(f32x4v*)&sT[j_l][dq * 8 + 4] = v1;
  }
  __syncthreads();
  const int jb_l = tid >> 6, l = tid & 63, l31 = l & 31, lhi = l >> 5;
  u16x8 o;
#pragma unroll
  for (int e = 0; e < 8; ++e) o[e] = f2bf(sT[jb_l * 16 + lhi * 8 + e][l31]);
  unsigned short* dst = ATf + (size_t)t * (8 * 256 * 64 * 8)
                      + ((size_t)(ds * 256 + jgrp * 4 + jb_l) * 64 + l) * 8;
  *(u16x8*)dst = o;
}

// ---- init: X -> Zf frags + erow ----
__global__ __launch_bounds__(256) void k_init(const float* __restrict__ X,
                                              unsigned short* __restrict__ Zf,
                                              float* __restrict__ erow) {
  const int tid = threadIdx.x;
  const int r = blockIdx.x * 8 + (tid >> 5), o = tid & 31;
  const size_t base = (size_t)r * DIM + o * 8;
  f32x4v z0 = *(const f32x4v*)(X + base), z1 = *(const f32x4v*)(X + base + 4);
  u16x8 zb; float s = 0.f;
#pragma unroll
  for (int i = 0; i < 4; ++i) { zb[i] = f2bf(z0[i]); zb[4 + i] = f2bf(z1[i]);
                                s += z0[i] * z0[i] + z1[i] * z1[i]; }
  *(u16x8*)(Zf + ((size_t)((r >> 5) * 16 + (o >> 1)) * 64 + (o & 1) * 32 + (r & 31)) * 8) = zb;
#pragma unroll
  for (int d = 16; d > 0; d >>= 1) s += __shfl_down(s, d, 32);
  if (o == 0) erow[r] = __expf(-s * C1);
}

// ---- fused flash (R18: af-resident producer, Zj double-buffered in LDS) ----
// grid (8 chunks, 64 i-tiles of 64 rows), 512 thr = 8 waves, 2 blocks/CU.
// waves 0-3 producer (ip=wid>>1, jh=wid&1): S = Zi(32) @ Zj(32)^T;
//   af[16] RESIDENT (global, once); bv from sZj[cur] (ds_read); producers
//   stage sZj[(n+1)&1] via 8x gload_lds16/thread. P -> sP[n&1].
// waves 4-7 consumer cd: O(64i x 64d) += P @ A_t; bw x8 from global/tile;
//   + affine slice ksg=chunk*2+{0,1} (a-frags from global, once).
__global__ __launch_bounds__(512, 4) void k_flash(
    const unsigned short* __restrict__ Zf, const float* __restrict__ erow,
    const unsigned short* __restrict__ ATf_t,
    const float* __restrict__ Aaff_t,
    unsigned short* __restrict__ Opart) {
  __shared__ __align__(16) unsigned short sP[2][64 * 64];       // 2 x 8KB swizzled
  __shared__ __align__(16) unsigned short sZj[2][2 * 16 * 64 * 8]; // 2 x 32KB

  const int tid = threadIdx.x, lane = tid & 63, wid = tid >> 6;
  const int l31 = lane & 31, lhi = lane >> 5;
  const int chunk = blockIdx.x;
  const int i0 = blockIdx.y * 64;
  const int ib = i0 >> 5;
  const unsigned short* zib = Zf + (size_t)ib * 8192;           // 64 i-rows, frag-linear
  const unsigned short* zjs = Zf + (size_t)(chunk * 16) * 8192; // chunk j-region

  if (wid < 4) {
    // ================= producer =================
    const int ip = wid >> 1, jh = wid & 1;

    // stage tile 0 (32KB over 256 producer threads: 8 x 16B each)
#pragma unroll
    for (int p = 0; p < 8; ++p)
      gload_lds16(zjs + (size_t)(p * 256 + tid) * 8,
                  sZj[0] + (size_t)(p * 256 + tid) * 8);

    // af[16] resident: wave's 32 i-rows x K=256, from global (once)
    u32x4 af[16];
#pragma unroll
    for (int ks = 0; ks < 16; ++ks)
      af[ks] = *(const u32x4*)(zib + ((size_t)(ip * 16 + ks) * 64 + lane) * 8);

    const float* eIb = erow + i0 + ip * 32 + 4 * lhi;   // + (c&3) + 8*(c>>2)
    __syncthreads();   // stage barrier: sZj[0] ready (vmcnt drained)

    for (int n = 0; n < 8; ++n) {
      const int cur = n & 1;
      // stage tile n+1 into the other buffer (async; drained at barrier)
      if (n < 7) {
        const unsigned short* src = zjs + (size_t)(n + 1) * 16384;
#pragma unroll
        for (int p = 0; p < 8; ++p)
          gload_lds16(src + (size_t)(p * 256 + tid) * 8,
                      sZj[cur ^ 1] + (size_t)(p * 256 + tid) * 8);
      }
      // S chain: af (regs) x bv (LDS ds_read_b128, ~120cyc, prefetchable)
      f32x16 S;
#pragma unroll
      for (int i = 0; i < 16; ++i) S[i] = 0.f;
      __builtin_amdgcn_s_setprio(1);
#pragma unroll
      for (int ks = 0; ks < 16; ++ks) {
        bf16x8 bv = *(const bf16x8*)(sZj[cur] + ((size_t)(jh * 16 + ks) * 64 + lane) * 8);
        S = __builtin_amdgcn_mfma_f32_32x32x16_bf16(
            __builtin_bit_cast(bf16x8, af[ks]), bv, S, 0, 0, 0);
      }
      __builtin_amdgcn_s_setprio(0);
      const float ej = erow[chunk * 512 + n * 64 + jh * 32 + l31];
      unsigned short* pb = sP[n & 1];
      const int blk = jh * 4 + (l31 >> 3), cl = l31 & 7;
#pragma unroll
      for (int c = 0; c < 16; ++c) {
        const int row = ip * 32 + 4 * lhi + (c & 3) + 8 * (c >> 2);
        const float eIc = eIb[(c & 3) + 8 * (c >> 2)];   // L1-hot broadcast
        pb[row * 64 + ((blk ^ (row & 7)) * 8) + cl] =
            f2bf(eIc * ej * __expf(2.f * C1 * S[c]));
      }
      __syncthreads();
    }
    __syncthreads();   // match consumer's final barrier
  } else {
    // ================= consumer =================
    const int cd = wid - 4;
    f32x16 O[2][2];
#pragma unroll
    for (int rs = 0; rs < 2; ++rs)
#pragma unroll
      for (int ct = 0; ct < 2; ++ct)
#pragma unroll
        for (int i = 0; i < 16; ++i) O[rs][ct][i] = 0.f;

    // affine slice (unscaled): ksg = chunk*2+{0,1}; a-frags from GLOBAL
#pragma unroll
    for (int q = 0; q < 2; ++q) {
      const int ksg = chunk * 2 + q;
      bf16x8 a[2];
#pragma unroll
      for (int rs = 0; rs < 2; ++rs)
        a[rs] = *(const bf16x8*)(zib + ((size_t)(rs * 16 + ksg) * 64 + lane) * 8);
#pragma unroll
      for (int ct = 0; ct < 2; ++ct) {
        const int d = cd * 64 + ct * 32 + l31;
        const float* bp = Aaff_t + (size_t)d * DIM + ksg * 16 + lhi * 8;
        f32x4v f0 = *(const f32x4v*)bp, f1 = *(const f32x4v*)(bp + 4);
        u16x8 tb;
#pragma unroll
        for (int i = 0; i < 4; ++i) { tb[i] = f2bf(f0[i]); tb[4 + i] = f2bf(f1[i]); }
        bf16x8 bv = __builtin_bit_cast(bf16x8, tb);
#pragma unroll
        for (int rs = 0; rs < 2; ++rs)
          O[rs][ct] = __builtin_amdgcn_mfma_f32_32x32x16_bf16(a[rs], bv, O[rs][ct], 0, 0, 0);
      }
    }
    __syncthreads();   // stage barrier (producers staged sZj[0])
    __syncthreads();   // barrier 1 (producer finished tile 0)

    for (int n = 1; n <= 8; ++n) {
      const int m = n - 1;
      // hoist the 8 ATf b-frags (R14 placement)
      u32x4 bw[8];
#pragma unroll
      for (int ks = 0; ks < 4; ++ks)
#pragma unroll
        for (int ct = 0; ct < 2; ++ct)
          bw[ks * 2 + ct] = *(const u32x4*)(ATf_t +
              ((size_t)((cd * 2 + ct) * 256 + chunk * 32 + m * 4 + ks) * 64 + lane) * 8);
      const unsigned short* pb = sP[m & 1];
#pragma unroll
      for (int ks = 0; ks < 4; ++ks) {
        bf16x8 a[2];
        const int blk = ks * 2 + lhi;
#pragma unroll
        for (int rs = 0; rs < 2; ++rs) {
          const int row = rs * 32 + l31;
          a[rs] = *(const bf16x8*)&pb[row * 64 + ((blk ^ (row & 7)) * 8)];
        }
        __builtin_amdgcn_s_setprio(1);
#pragma unroll
        for (int rs = 0; rs < 2; ++rs)
#pragma unroll
          for (int ct = 0; ct < 2; ++ct)
            O[rs][ct] = __builtin_amdgcn_mfma_f32_32x32x16_bf16(
                a[rs], __builtin_bit_cast(bf16x8, bw[ks * 2 + ct]), O[rs][ct], 0, 0, 0);
        __builtin_amdgcn_s_setprio(0);
      }
      __syncthreads();
    }

    // epilogue -> Opart[chunk] bf16 (P already carries ei*ej)
    unsigned short* ob = Opart + (size_t)chunk * N_PTS * DIM + (size_t)cd * 64 + l31;
#pragma unroll
    for (int rs = 0; rs < 2; ++rs)
#pragma unroll
      for (int c = 0; c < 16; ++c) {
        const int row = i0 + rs * 32 + 4 * lhi + (c & 3) + 8 * (c >> 2);
        ob[(size_t)row * DIM]      = f2bf(O[rs][0][c]);
        ob[(size_t)row * DIM + 32] = f2bf(O[rs][1][c]);
      }
  }
}

// ---- update: Z += DT*(sum partials + baff); emit Zf frags + erow ----
__global__ __launch_bounds__(256) void k_update(const float* __restrict__ Zin,
                                                const unsigned short* __restrict__ Opart,
                                                const float* __restrict__ baff_t,
                                                float* __restrict__ Zout,
                                                unsigned short* __restrict__ Zf,
                                                float* __restrict__ erow) {
  const int tid = threadIdx.x;
  const int r = blockIdx.x * 8 + (tid >> 5), o = tid & 31;
  const size_t base = (size_t)r * DIM + o * 8;
  f32x4v z0 = *(const f32x4v*)(Zin + base), z1 = *(const f32x4v*)(Zin + base + 4);
  f32x4v s0 = *(const f32x4v*)(baff_t + o * 8), s1 = *(const f32x4v*)(baff_t + o * 8 + 4);
#pragma unroll
  for (int c = 0; c < 8; ++c) {
    u16x8 p = *(const u16x8*)(Opart + (size_t)c * N_PTS * DIM + base);
#pragma unroll
    for (int i = 0; i < 4; ++i) { s0[i] += bf2f(p[i]); s1[i] += bf2f(p[4 + i]); }
  }
  u16x8 zb; float sv = 0.f;
#pragma unroll
  for (int i = 0; i < 4; ++i) {
    z0[i] += DT_C * s0[i]; z1[i] += DT_C * s1[i];
    zb[i] = f2bf(z0[i]); zb[4 + i] = f2bf(z1[i]);
    sv += z0[i] * z0[i] + z1[i] * z1[i];
  }
  *(f32x4v*)(Zout + base) = z0;
  *(f32x4v*)(Zout + base + 4) = z1;
  *(u16x8*)(Zf + ((size_t)((r >> 5) * 16 + (o >> 1)) * 64 + (o & 1) * 32 + (r & 31)) * 8) = zb;
#pragma unroll
  for (int d = 16; d > 0; d >>= 1) sv += __shfl_down(sv, d, 32);
  if (o == 0) erow[r] = __expf(-sv * C1);
}

extern "C" void kernel_launch(void* const* d_in, const int* in_sizes, int n_in,
                              void* d_out, int out_size, void* d_ws, size_t ws_size,
                              hipStream_t stream) {
  const float* X    = (const float*)d_in[0];
  const float* A    = (const float*)d_in[1];
  const float* Aaff = (const float*)d_in[2];
  const float* baff = (const float*)d_in[3];
  float* out = (float*)d_out;

  char* w = (char*)d_ws;
  size_t off = 0;
  unsigned short* ATf = (unsigned short*)(w + off); off += (size_t)8 * 8 * 256 * 64 * 8 * 2; // 16 MiB
  unsigned short* Zf  = (unsigned short*)(w + off); off += (size_t)N_PTS * DIM * 2;          // 2 MiB
  float* erow = (float*)(w + off); off += (size_t)N_PTS * 4;
  float* Zf32 = (float*)(w + off); off += (size_t)N_PTS * DIM * 4;                           // 4 MiB
  unsigned short* Opart = (unsigned short*)(w + off); off += (size_t)8 * N_PTS * DIM * 2;    // 16 MiB
  (void)ws_size; (void)in_sizes; (void)n_in; (void)out_size;

  k_prep<<<dim3(64, 8, 8), 256, 0, stream>>>(A, ATf);
  k_init<<<512, 256, 0, stream>>>(X, Zf, erow);

  const float* zin = X;
  for (int t = 0; t < 8; ++t) {
    float* zout = (t == 7) ? out : Zf32;  // in-place safe after t=0
    k_flash<<<dim3(8, 64), 512, 0, stream>>>(
        Zf, erow, ATf + (size_t)t * (8 * 256 * 64 * 8), Aaff + (size_t)t * DIM * DIM, Opart);
    k_update<<<512, 256, 0, stream>>>(zin, Opart, baff + (size_t)t * DIM, zout, Zf, erow);
    zin = zout;
  }
}